// Round 24
// baseline (60.196 us; speedup 1.0000x reference)
//
#include <hip/hip_runtime.h>
#include <math.h>

#define NB 2
#define NL 2048
#define NK 30
#define NEF 128
#define NEIN 416
#define BM 64            // edges per block in k_edge
#define FROW 424         // fA row stride (bytes): conflict-free quarter-wave b64 reads
#define SROW 132         // staging row stride (floats)

typedef float f32x4 __attribute__((ext_vector_type(4)));
typedef unsigned long long ull;

__constant__ int c_PA[24] = {0,2,3,4,1,1,1,1,0,0,0,4,4,3,0,2,3,4,2,3,4,2,3,2};
__constant__ int c_PB[24] = {0,2,3,4,0,2,3,4,2,3,4,2,3,2,1,1,1,1,0,0,0,4,4,3};

__device__ inline ull umin64(ull a, ull b) { return a < b ? a : b; }
__device__ inline ull umax64(ull a, ull b) { return a > b ? a : b; }

// ---- DPP add (VALU only).
template<int CTRL>
__device__ inline float dpp_add(float v) {
    int x = __builtin_amdgcn_update_dpp(0, __float_as_int(v), CTRL, 0xF, 0xF, true);
    return v + __int_as_float(x);
}

// ---- 64-lane u64 min: DPP for xor1..8, ds_swizzle for xor16, shfl for xor32.
template<int CTRL>
__device__ inline ull dpp_min64(ull v) {
    int lo = __builtin_amdgcn_update_dpp(0, (int)(unsigned)(v & 0xffffffffULL), CTRL, 0xF, 0xF, true);
    int hi = __builtin_amdgcn_update_dpp(0, (int)(unsigned)(v >> 32), CTRL, 0xF, 0xF, true);
    ull o = ((ull)(unsigned)hi << 32) | (unsigned)lo;
    return o < v ? o : v;
}
__device__ inline ull wave_min64(ull v) {
    v = dpp_min64<0xB1>(v);
    v = dpp_min64<0x4E>(v);
    v = dpp_min64<0x141>(v);
    v = dpp_min64<0x140>(v);
    {   // xor16 within each 32-lane half (BitMode: xor=16, and=0x1F)
        int lo = __builtin_amdgcn_ds_swizzle((int)(unsigned)(v & 0xffffffffULL), 0x401F);
        int hi = __builtin_amdgcn_ds_swizzle((int)(unsigned)(v >> 32), 0x401F);
        ull o = ((ull)(unsigned)hi << 32) | (unsigned)lo;
        v = o < v ? o : v;
    }
    {   // xor32
        int lo = __shfl_xor((int)(unsigned)(v & 0xffffffffULL), 32);
        int hi = __shfl_xor((int)(unsigned)(v >> 32), 32);
        ull o = ((ull)(unsigned)hi << 32) | (unsigned)lo;
        v = o < v ? o : v;
    }
    return v;
}

// ---- kernel 1 (merged front): blocks 0..511 = topk (coalesced float4 staging);
//      blocks 512..519 = atoms5 prep; blocks 520..571 = Wt fp8 prep.
__global__ __launch_bounds__(512, 4) void k_front(const float* __restrict__ X,
                                                  const float* __restrict__ mask,
                                                  const float* __restrict__ eW,
                                                  float4* __restrict__ atoms5,
                                                  unsigned char* __restrict__ Wt,
                                                  float* __restrict__ dnb,
                                                  int*   __restrict__ eidx,
                                                  float* __restrict__ eidx_f)
{
    __shared__ float4 ca[NL];
    int t = threadIdx.x;

    if (blockIdx.x >= 512) {
        if (blockIdx.x < 520) {
            // atoms5: [N,Ca,C,O,Cb] as 5x float4 per residue
            int idx = (blockIdx.x - 512) * 512 + t;       // 8*512 = 4096
            const float* x = X + (size_t)idx * 12;
            float N[3], Ca[3], C[3], O[3], bv[3], cv[3], av[3];
#pragma unroll
            for (int d = 0; d < 3; d++) { N[d] = x[d]; Ca[d] = x[3+d]; C[d] = x[6+d]; O[d] = x[9+d]; }
#pragma unroll
            for (int d = 0; d < 3; d++) { bv[d] = Ca[d] - N[d]; cv[d] = C[d] - Ca[d]; }
            av[0] = bv[1]*cv[2] - bv[2]*cv[1];
            av[1] = bv[2]*cv[0] - bv[0]*cv[2];
            av[2] = bv[0]*cv[1] - bv[1]*cv[0];
            float4* o = atoms5 + (size_t)idx * 5;
            o[0] = make_float4(N[0], N[1], N[2], 0.f);
            o[1] = make_float4(Ca[0], Ca[1], Ca[2], 0.f);
            o[2] = make_float4(C[0], C[1], C[2], 0.f);
            o[3] = make_float4(O[0], O[1], O[2], 0.f);
            float cb0 = -0.58273431f*av[0] + 0.56802827f*bv[0] - 0.54067466f*cv[0] + Ca[0];
            float cb1 = -0.58273431f*av[1] + 0.56802827f*bv[1] - 0.54067466f*cv[1] + Ca[1];
            float cb2 = -0.58273431f*av[2] + 0.56802827f*bv[2] - 0.54067466f*cv[2] + Ca[2];
            o[4] = make_float4(cb0, cb1, cb2, 0.f);
        } else {
            // Wt: W (416x128 f32) -> (128x416 fp8 e4m3)
            int idx = (blockIdx.x - 520) * 512 + t;       // 52*512 = 26624
            if (idx < NEF * (NEIN / 2)) {
                int c  = idx / (NEIN / 2);
                int k2 = idx - c * (NEIN / 2);
                float a = eW[(size_t)(2 * k2) * NEF + c];
                float b = eW[(size_t)(2 * k2 + 1) * NEF + c];
                int r = __builtin_amdgcn_cvt_pk_fp8_f32(a, b, 0, false);
                *(unsigned short*)&Wt[(size_t)c * NEIN + 2 * k2] = (unsigned short)(r & 0xffff);
            }
        }
        return;
    }

    // ---- topk: 8 rows per block, one wave per row; coalesced float4 staging.
    int base = blockIdx.x << 3;
    int b = base >> 11;
    const float4* X4 = (const float4*)(X + (size_t)b * NL * 12);   // 3 float4/residue
    const float* mb = mask + (size_t)b * NL;
#pragma unroll
    for (int r = 0; r < NL/512; r++) {
        int j = t + r * 512;
        float4 a0 = X4[(size_t)j * 3 + 0];   // N.xyz, Ca.x
        float4 a1 = X4[(size_t)j * 3 + 1];   // Ca.yz, C.xy
        ca[j] = make_float4(a0.w, a1.x, a1.y, mb[j]);
    }
    __syncthreads();

    int w = t >> 6, lane = t & 63;
    int row = base + w;
    int i = row & (NL - 1);
    float4 ci = ca[i];
    float mi = ci.w;

    float df[32];
    unsigned mflags = 0;
    float lmax = 0.0f;
#pragma unroll
    for (int r = 0; r < 32; r++) {
        float4 cj = ca[r*64 + lane];
        float dx = __fsub_rn(ci.x, cj.x);
        float dy = __fsub_rn(ci.y, cj.y);
        float dz = __fsub_rn(ci.z, cj.z);
        float s  = __fadd_rn(__fadd_rn(__fmul_rn(dx,dx), __fmul_rn(dy,dy)), __fmul_rn(dz,dz));
        s = __fadd_rn(s, 1e-6f);
        float m2 = __fmul_rn(mi, cj.w);   // binary mask: 0 or 1
        float d  = __fmul_rn(m2, __fsqrt_rn(s));
        df[r] = d;
        lmax = fmaxf(lmax, d);
        mflags |= (m2 != 0.0f) ? (1u << r) : 0u;
    }
#pragma unroll
    for (int off = 32; off; off >>= 1) lmax = fmaxf(lmax, __shfl_xor(lmax, off));
    unsigned rmb = __float_as_uint(lmax);

    const ull INF = ~0ULL;
    ull m0 = INF, m1 = INF, m2k = INF, m3 = INF;
#pragma unroll
    for (int r = 0; r < 32; r++) {
        unsigned hi = ((mflags >> r) & 1u) ? __float_as_uint(df[r]) : rmb;
        ull key = ((ull)hi << 32) | (unsigned)(r*64 + lane);
        ull a0 = umin64(key, m0); ull k1 = umax64(key, m0); m0 = a0;
        ull a1 = umin64(k1, m1);  ull k2 = umax64(k1, m1);  m1 = a1;
        ull a2 = umin64(k2, m2k); ull k3 = umax64(k2, m2k); m2k = a2;
        m3 = umin64(k3, m3);
    }

    int c = 0;
    ull mykey = 0;
    for (int sel = 0; sel < NK; sel++) {
        ull g = wave_min64(m0);
        if (m0 == g) {
            m0 = m1; m1 = m2k; m2k = m3; m3 = INF;
            c++;
            if (m0 == INF && c < 32) {
#pragma unroll
                for (int r = 0; r < 32; r++) {
                    unsigned hi = ((mflags >> r) & 1u) ? __float_as_uint(df[r]) : rmb;
                    ull key = ((ull)hi << 32) | (unsigned)(r*64 + lane);
                    if (key > g) {
                        ull a0 = umin64(key, m0); ull k1 = umax64(key, m0); m0 = a0;
                        ull a1 = umin64(k1, m1);  ull k2 = umax64(k1, m1);  m1 = a1;
                        ull a2 = umin64(k2, m2k); ull k3 = umax64(k2, m2k); m2k = a2;
                        m3 = umin64(k3, m3);
                    }
                }
            }
        }
        mykey = (lane == sel) ? g : mykey;
    }
    if (lane < NK) {
        int g = row * NK + lane;
        int j = (int)(mykey & 0xffffffffULL);
        dnb[g]    = __uint_as_float((unsigned)(mykey >> 32));
        eidx[g]   = j;
        eidx_f[g] = (float)j;
    }
}

// ------- kernel 2: features(fp8) + fp8 MFMA GEMM + LayerNorm, 512 thr / 8 waves -------
// r22 winner: raw-acc staging -> cooperative row-stats -> normalize-in-store.
__global__ __launch_bounds__(512, 4) void k_edge(const float4* __restrict__ atoms5,
                                              const int*   __restrict__ eidx,
                                              const float* __restrict__ dnb,
                                              const int*   __restrict__ ridx,
                                              const int*   __restrict__ chl,
                                              const float* __restrict__ posW,
                                              const float* __restrict__ posb,
                                              const unsigned char* __restrict__ Wt,
                                              const float* __restrict__ lns,
                                              const float* __restrict__ lno,
                                              float* __restrict__ Eout)
{
    // LDS union: phase A: fA[64][424]=27136 + acache[64][10]f4=10240 -> 37376
    //            phase B: staging[64][132]f = 33792 (overlaps fA)
    //            dedicated: red2[64][2]f at 37376 (1024 B) -> total 38400
    __shared__ __align__(16) unsigned char smem[38400];
    unsigned char (*fA)[FROW] = (unsigned char (*)[FROW])smem;
    float4* acache = (float4*)(smem + 27136);      // [64][10]
    float*  staging = (float*)smem;                // [64][SROW]
    float*  red2    = (float*)(smem + 37376);      // [64][2]: rs, mu*rs
    int t = threadIdx.x;
    int base = blockIdx.x * BM;

    int w    = t >> 6;
    int lane = t & 63;
    int l16  = lane & 15;
    int lg   = lane >> 4;
    int g8   = lg * 8;
    int ncol = w * 16;

    // ---- prefetch edge metadata FIRST (L2 latency overlaps B preload).
    int e0 = t >> 3;
    int q  = t & 7;
    int g  = base + e0;
    int j0 = eidx[g];
    int gi = g / 30;                  // exact
    int b_ = gi >> 11;

    // ---- B preload: 13 x 8B independent loads; latency hides under phase 1.
    const unsigned char* wtb = Wt + (size_t)(ncol + l16) * NEIN + g8;
    long bfr[13];
#pragma unroll
    for (int kt = 0; kt < 13; kt++)
        bfr[kt] = *(const long*)(wtb + kt * 32);

    // ---- phase 1: features, p-split, fp8-packed, 2-head recurrence RBF.
    {
        int gj = (b_ << 11) + j0;

        const float4* A4 = atoms5 + (size_t)gi * 5;
        const float4* B4 = atoms5 + (size_t)gj * 5;
        float4* ac = acache + e0 * 10;
        ac[q] = (q < 5) ? A4[q] : B4[q - 5];
        if (q < 2) ac[8 + q] = B4[3 + q];
        __builtin_amdgcn_wave_barrier();

        int off = ridx[gi] - ridx[gj];
        int ec  = (chl[gi] == chl[gj]) ? 1 : 0;
        int dp  = min(max(off + 32, 0), 64);
        dp = ec ? dp : 65;
        {
            float p0 = posW[dp * 16 + 2*q]     + posb[2*q];
            float p1 = posW[dp * 16 + 2*q + 1] + posb[2*q + 1];
            int r = __builtin_amdgcn_cvt_pk_fp8_f32(p0, p1, 0, false);
            *(unsigned short*)&fA[e0][q * 2] = (unsigned short)(r & 0xffff);
        }

        // exp(-(0.8(D-mu_s))^2) = 2^(-(aD - c_s)^2); recurrence over s, 2 heads.
        const float A_ = 0.96089792711f;          // 0.8*sqrt(log2 e)
        const float C0 = 1.92179585422f;          // A_*2
        const float CS = 1.28119723615f;          // A_*(4/3)
        const float E8 = 10.24957789f;            // 8*CS
        const float QQ = __builtin_amdgcn_exp2f(-2.0f * CS * CS);
        auto body = [&](int p) {
            float D;
            if (p == 0) {
                D = dnb[g];
            } else {
                float4 a  = ac[c_PA[p - 1]];
                float4 bb = ac[5 + c_PB[p - 1]];
                float dx = a.x - bb.x, dy = a.y - bb.y, dz = a.z - bb.z;
                D = __builtin_amdgcn_sqrtf(dx*dx + dy*dy + dz*dz + 1e-6f);
            }
            float u0 = D * A_ - C0;
            float f  = __builtin_amdgcn_exp2f(-(u0 * u0));
            float rr = __builtin_amdgcn_exp2f(CS * (2.0f * u0 - CS));
            int wds[4];
#pragma unroll
            for (int gq = 0; gq < 4; gq++) {
                if (gq == 2) {                       // re-seed head at s=8
                    float u8 = u0 - E8;
                    f = __builtin_amdgcn_exp2f(-(u8 * u8));
                }
                float v[4];
#pragma unroll
                for (int u = 0; u < 4; u++) {
                    v[u] = f;
                    f  *= rr;
                    rr *= QQ;
                }
                int r = __builtin_amdgcn_cvt_pk_fp8_f32(v[0], v[1], 0, false);
                r = __builtin_amdgcn_cvt_pk_fp8_f32(v[2], v[3], r, true);
                wds[gq] = r;
            }
            long lo = ((long)(unsigned)wds[1] << 32) | (unsigned)wds[0];
            long hi = ((long)(unsigned)wds[3] << 32) | (unsigned)wds[2];
            *(long*)&fA[e0][16 + p * 16]     = lo;
            *(long*)&fA[e0][16 + p * 16 + 8] = hi;
        };

#pragma unroll
        for (int pp = 0; pp < 3; pp++) body(q + pp * 8);
        if (q == 0) body(24);
    }

    __syncthreads();                               // B1

    // ---- phase 2: GEMM. 52 MFMA + 52 conflict-free ds_read_b64 per wave.
    f32x4 acc[4];
#pragma unroll
    for (int mt = 0; mt < 4; mt++) acc[mt] = (f32x4){0.f, 0.f, 0.f, 0.f};

#pragma unroll
    for (int kt = 0; kt < 13; kt++) {
#pragma unroll
        for (int mt = 0; mt < 4; mt++) {
            long a = *(const long*)(&fA[mt * 16 + l16][kt * 32 + g8]);
            acc[mt] = __builtin_amdgcn_mfma_f32_16x16x32_fp8_fp8(a, bfr[kt], acc[mt], 0, 0, 0);
        }
    }

    __syncthreads();                               // B2: all fA reads done -> staging safe

    // ---- phase 3: stage RAW acc values (no math).
#pragma unroll
    for (int mt = 0; mt < 4; mt++)
#pragma unroll
        for (int r = 0; r < 4; r++) {
            int row = mt * 16 + lg * 4 + r;
            staging[row * SROW + ncol + l16] = acc[mt][r];
        }
    __syncthreads();                               // B3

    // ---- stats: 8 threads per row; 4x b128 reads + 3-step DPP tree over s.
    {
        int row = t >> 3, s = t & 7;
        float ts = 0.f, tq = 0.f;
#pragma unroll
        for (int u = 0; u < 4; u++) {
            f32x4 v = *(f32x4*)&staging[row * SROW + s * 16 + u * 4];
            ts += v.x + v.y + v.z + v.w;
            tq = fmaf(v.x, v.x, tq); tq = fmaf(v.y, v.y, tq);
            tq = fmaf(v.z, v.z, tq); tq = fmaf(v.w, v.w, tq);
        }
        ts = dpp_add<0xB1>(ts); ts = dpp_add<0x4E>(ts); ts = dpp_add<0x141>(ts);
        tq = dpp_add<0xB1>(tq); tq = dpp_add<0x4E>(tq); tq = dpp_add<0x141>(tq);
        if (s == 0) {
            float mu  = ts * (1.0f / 128.0f);
            float var = tq * (1.0f / 128.0f) - mu * mu;
            float rs  = 1.0f / sqrtf(var + 1e-5f);
            red2[row * 2 + 0] = rs;
            red2[row * 2 + 1] = mu * rs;
        }
    }
    __syncthreads();                               // B4

    // ---- phase 4: store loop with inline normalize (2 FMA/elem), full-line stream.
    int c4s = t & 31;
    f32x4 sc4 = *(const f32x4*)&lns[c4s * 4];
    f32x4 of4 = *(const f32x4*)&lno[c4s * 4];
    f32x4* Eout4 = (f32x4*)Eout;
#pragma unroll
    for (int u = 0; u < 4; u++) {
        int idx  = u * 512 + t;                    // 0..2047
        int lrow = idx >> 5;
        f32x4 v = *(f32x4*)&staging[lrow * SROW + c4s * 4];
        float rs   = red2[lrow * 2 + 0];
        float murs = red2[lrow * 2 + 1];
        f32x4 o;
        o.x = fmaf(sc4.x, fmaf(v.x, rs, -murs), of4.x);
        o.y = fmaf(sc4.y, fmaf(v.y, rs, -murs), of4.y);
        o.z = fmaf(sc4.z, fmaf(v.z, rs, -murs), of4.z);
        o.w = fmaf(sc4.w, fmaf(v.w, rs, -murs), of4.w);
        Eout4[(size_t)(base + lrow) * 32 + c4s] = o;
    }
    // no trailing barrier: stores drain as waves retire
}

extern "C" void kernel_launch(void* const* d_in, const int* in_sizes, int n_in,
                              void* d_out, int out_size, void* d_ws, size_t ws_size,
                              hipStream_t stream)
{
    const float* X    = (const float*)d_in[0];
    const float* mask = (const float*)d_in[1];
    const int*   ridx = (const int*)d_in[2];
    const int*   chl  = (const int*)d_in[3];
    const float* posW = (const float*)d_in[4];
    const float* posb = (const float*)d_in[5];
    const float* eW   = (const float*)d_in[6];
    const float* lns  = (const float*)d_in[7];
    const float* lno  = (const float*)d_in[8];

    float* Eout   = (float*)d_out;                                  // B*L*K*128
    float* eidx_f = Eout + (size_t)NB * NL * NK * NEF;              // B*L*K (as float)

    char* ws = (char*)d_ws;
    float4*        atoms5 = (float4*)ws;                            // 327680 B
    float*         dnb    = (float*)(ws + 327680);                  // 491520 B
    int*           eidx   = (int*)(ws + 819200);                    // 491520 B
    unsigned char* Wt     = (unsigned char*)(ws + 1310720);         // 53248 B

    k_front<<<572, 512, 0, stream>>>(X, mask, eW, atoms5, Wt, dnb, eidx, eidx_f);
    k_edge<<<(NB * NL * NK) / BM, 512, 0, stream>>>(atoms5, eidx, dnb, ridx, chl,
                                                    posW, posb, Wt, lns, lno, Eout);
}

// Round 25
// 59.254 us; speedup vs baseline: 1.0159x; 1.0159x over previous
//
#include <hip/hip_runtime.h>
#include <math.h>

#define NB 2
#define NL 2048
#define NK 30
#define NEF 128
#define NEIN 416
#define BM 64            // edges per block in k_edge
#define FROW 424         // fA row stride (bytes): conflict-free quarter-wave b64 reads
#define SROW 132         // staging row stride (floats)

typedef float f32x4 __attribute__((ext_vector_type(4)));
typedef unsigned long long ull;

__constant__ int c_PA[24] = {0,2,3,4,1,1,1,1,0,0,0,4,4,3,0,2,3,4,2,3,4,2,3,2};
__constant__ int c_PB[24] = {0,2,3,4,0,2,3,4,2,3,4,2,3,2,1,1,1,1,0,0,0,4,4,3};

__device__ inline ull umin64(ull a, ull b) { return a < b ? a : b; }
__device__ inline ull umax64(ull a, ull b) { return a > b ? a : b; }

// ---- DPP add (VALU only).
template<int CTRL>
__device__ inline float dpp_add(float v) {
    int x = __builtin_amdgcn_update_dpp(0, __float_as_int(v), CTRL, 0xF, 0xF, true);
    return v + __int_as_float(x);
}

// ---- u64 min with DPP shuffle (invalid lanes -> 0-filled, only used for
//      mirror modes where every lane has a valid source).
template<int CTRL>
__device__ inline ull dpp_min64(ull v) {
    int lo = __builtin_amdgcn_update_dpp(0, (int)(unsigned)(v & 0xffffffffULL), CTRL, 0xF, 0xF, true);
    int hi = __builtin_amdgcn_update_dpp(0, (int)(unsigned)(v >> 32), CTRL, 0xF, 0xF, true);
    ull o = ((ull)(unsigned)hi << 32) | (unsigned)lo;
    return o < v ? o : v;
}
// ---- u64 min with DPP bcast modes; non-target lanes KEEP v (old = v,
//      bound_ctrl=false) which is the identity for min.
template<int CTRL>
__device__ inline ull dpp_min64_keep(ull v) {
    int vlo = (int)(unsigned)(v & 0xffffffffULL);
    int vhi = (int)(unsigned)(v >> 32);
    int lo = __builtin_amdgcn_update_dpp(vlo, vlo, CTRL, 0xF, 0xF, false);
    int hi = __builtin_amdgcn_update_dpp(vhi, vhi, CTRL, 0xF, 0xF, false);
    ull o = ((ull)(unsigned)hi << 32) | (unsigned)lo;
    return o < v ? o : v;
}
// ---- wave-wide u64 min, pure-VALU chain + scalar broadcast:
//      4 mirror levels (proven) -> row-uniform; ROW_BCAST15 merges row pairs,
//      ROW_BCAST31 merges halves; lane 63 holds the global min; readlane bcasts.
__device__ inline ull wave_min64(ull v) {
    v = dpp_min64<0xB1>(v);         // quad_perm xor1
    v = dpp_min64<0x4E>(v);         // quad_perm xor2
    v = dpp_min64<0x141>(v);        // row_half_mirror == xor4
    v = dpp_min64<0x140>(v);        // row_mirror      == xor8
    v = dpp_min64_keep<0x142>(v);   // row_bcast15: lanes16-31<=r0min, 48-63<=r2min
    v = dpp_min64_keep<0x143>(v);   // row_bcast31: lanes32-63<=min(r0,r1)
    unsigned lo = (unsigned)__builtin_amdgcn_readlane((int)(unsigned)(v & 0xffffffffULL), 63);
    unsigned hi = (unsigned)__builtin_amdgcn_readlane((int)(unsigned)(v >> 32), 63);
    return ((ull)hi << 32) | lo;
}

// ---- kernel 1 (merged front): blocks 0..511 = topk (coalesced float4 staging);
//      blocks 512..519 = atoms5 prep; blocks 520..571 = Wt fp8 prep.
__global__ __launch_bounds__(512, 4) void k_front(const float* __restrict__ X,
                                                  const float* __restrict__ mask,
                                                  const float* __restrict__ eW,
                                                  float4* __restrict__ atoms5,
                                                  unsigned char* __restrict__ Wt,
                                                  float* __restrict__ dnb,
                                                  int*   __restrict__ eidx,
                                                  float* __restrict__ eidx_f)
{
    __shared__ float4 ca[NL];
    int t = threadIdx.x;

    if (blockIdx.x >= 512) {
        if (blockIdx.x < 520) {
            // atoms5: [N,Ca,C,O,Cb] as 5x float4 per residue
            int idx = (blockIdx.x - 512) * 512 + t;       // 8*512 = 4096
            const float* x = X + (size_t)idx * 12;
            float N[3], Ca[3], C[3], O[3], bv[3], cv[3], av[3];
#pragma unroll
            for (int d = 0; d < 3; d++) { N[d] = x[d]; Ca[d] = x[3+d]; C[d] = x[6+d]; O[d] = x[9+d]; }
#pragma unroll
            for (int d = 0; d < 3; d++) { bv[d] = Ca[d] - N[d]; cv[d] = C[d] - Ca[d]; }
            av[0] = bv[1]*cv[2] - bv[2]*cv[1];
            av[1] = bv[2]*cv[0] - bv[0]*cv[2];
            av[2] = bv[0]*cv[1] - bv[1]*cv[0];
            float4* o = atoms5 + (size_t)idx * 5;
            o[0] = make_float4(N[0], N[1], N[2], 0.f);
            o[1] = make_float4(Ca[0], Ca[1], Ca[2], 0.f);
            o[2] = make_float4(C[0], C[1], C[2], 0.f);
            o[3] = make_float4(O[0], O[1], O[2], 0.f);
            float cb0 = -0.58273431f*av[0] + 0.56802827f*bv[0] - 0.54067466f*cv[0] + Ca[0];
            float cb1 = -0.58273431f*av[1] + 0.56802827f*bv[1] - 0.54067466f*cv[1] + Ca[1];
            float cb2 = -0.58273431f*av[2] + 0.56802827f*bv[2] - 0.54067466f*cv[2] + Ca[2];
            o[4] = make_float4(cb0, cb1, cb2, 0.f);
        } else {
            // Wt: W (416x128 f32) -> (128x416 fp8 e4m3)
            int idx = (blockIdx.x - 520) * 512 + t;       // 52*512 = 26624
            if (idx < NEF * (NEIN / 2)) {
                int c  = idx / (NEIN / 2);
                int k2 = idx - c * (NEIN / 2);
                float a = eW[(size_t)(2 * k2) * NEF + c];
                float b = eW[(size_t)(2 * k2 + 1) * NEF + c];
                int r = __builtin_amdgcn_cvt_pk_fp8_f32(a, b, 0, false);
                *(unsigned short*)&Wt[(size_t)c * NEIN + 2 * k2] = (unsigned short)(r & 0xffff);
            }
        }
        return;
    }

    // ---- topk: 8 rows per block, one wave per row; coalesced float4 staging.
    int base = blockIdx.x << 3;
    int b = base >> 11;
    const float4* X4 = (const float4*)(X + (size_t)b * NL * 12);   // 3 float4/residue
    const float* mb = mask + (size_t)b * NL;
#pragma unroll
    for (int r = 0; r < NL/512; r++) {
        int j = t + r * 512;
        float4 a0 = X4[(size_t)j * 3 + 0];   // N.xyz, Ca.x
        float4 a1 = X4[(size_t)j * 3 + 1];   // Ca.yz, C.xy
        ca[j] = make_float4(a0.w, a1.x, a1.y, mb[j]);
    }
    __syncthreads();

    int w = t >> 6, lane = t & 63;
    int row = base + w;
    int i = row & (NL - 1);
    float4 ci = ca[i];
    float mi = ci.w;

    float df[32];
    unsigned mflags = 0;
    float lmax = 0.0f;
#pragma unroll
    for (int r = 0; r < 32; r++) {
        float4 cj = ca[r*64 + lane];
        float dx = __fsub_rn(ci.x, cj.x);
        float dy = __fsub_rn(ci.y, cj.y);
        float dz = __fsub_rn(ci.z, cj.z);
        float s  = __fadd_rn(__fadd_rn(__fmul_rn(dx,dx), __fmul_rn(dy,dy)), __fmul_rn(dz,dz));
        s = __fadd_rn(s, 1e-6f);
        float m2 = __fmul_rn(mi, cj.w);   // binary mask: 0 or 1
        float d  = __fmul_rn(m2, __fsqrt_rn(s));
        df[r] = d;
        lmax = fmaxf(lmax, d);
        mflags |= (m2 != 0.0f) ? (1u << r) : 0u;
    }
#pragma unroll
    for (int off = 32; off; off >>= 1) lmax = fmaxf(lmax, __shfl_xor(lmax, off));
    unsigned rmb = __float_as_uint(lmax);

    const ull INF = ~0ULL;
    ull m0 = INF, m1 = INF, m2k = INF, m3 = INF;
#pragma unroll
    for (int r = 0; r < 32; r++) {
        unsigned hi = ((mflags >> r) & 1u) ? __float_as_uint(df[r]) : rmb;
        ull key = ((ull)hi << 32) | (unsigned)(r*64 + lane);
        ull a0 = umin64(key, m0); ull k1 = umax64(key, m0); m0 = a0;
        ull a1 = umin64(k1, m1);  ull k2 = umax64(k1, m1);  m1 = a1;
        ull a2 = umin64(k2, m2k); ull k3 = umax64(k2, m2k); m2k = a2;
        m3 = umin64(k3, m3);
    }

    int c = 0;
    ull mykey = 0;
    for (int sel = 0; sel < NK; sel++) {
        ull g = wave_min64(m0);
        if (m0 == g) {
            m0 = m1; m1 = m2k; m2k = m3; m3 = INF;
            c++;
            if (m0 == INF && c < 32) {
#pragma unroll
                for (int r = 0; r < 32; r++) {
                    unsigned hi = ((mflags >> r) & 1u) ? __float_as_uint(df[r]) : rmb;
                    ull key = ((ull)hi << 32) | (unsigned)(r*64 + lane);
                    if (key > g) {
                        ull a0 = umin64(key, m0); ull k1 = umax64(key, m0); m0 = a0;
                        ull a1 = umin64(k1, m1);  ull k2 = umax64(k1, m1);  m1 = a1;
                        ull a2 = umin64(k2, m2k); ull k3 = umax64(k2, m2k); m2k = a2;
                        m3 = umin64(k3, m3);
                    }
                }
            }
        }
        mykey = (lane == sel) ? g : mykey;
    }
    if (lane < NK) {
        int g = row * NK + lane;
        int j = (int)(mykey & 0xffffffffULL);
        dnb[g]    = __uint_as_float((unsigned)(mykey >> 32));
        eidx[g]   = j;
        eidx_f[g] = (float)j;
    }
}

// ------- kernel 2: features(fp8) + fp8 MFMA GEMM + LayerNorm, 512 thr / 8 waves -------
// r22 winner: raw-acc staging -> cooperative row-stats -> normalize-in-store.
__global__ __launch_bounds__(512, 4) void k_edge(const float4* __restrict__ atoms5,
                                              const int*   __restrict__ eidx,
                                              const float* __restrict__ dnb,
                                              const int*   __restrict__ ridx,
                                              const int*   __restrict__ chl,
                                              const float* __restrict__ posW,
                                              const float* __restrict__ posb,
                                              const unsigned char* __restrict__ Wt,
                                              const float* __restrict__ lns,
                                              const float* __restrict__ lno,
                                              float* __restrict__ Eout)
{
    // LDS union: phase A: fA[64][424]=27136 + acache[64][10]f4=10240 -> 37376
    //            phase B: staging[64][132]f = 33792 (overlaps fA)
    //            dedicated: red2[64][2]f at 37376 (1024 B) -> total 38400
    __shared__ __align__(16) unsigned char smem[38400];
    unsigned char (*fA)[FROW] = (unsigned char (*)[FROW])smem;
    float4* acache = (float4*)(smem + 27136);      // [64][10]
    float*  staging = (float*)smem;                // [64][SROW]
    float*  red2    = (float*)(smem + 37376);      // [64][2]: rs, mu*rs
    int t = threadIdx.x;
    int base = blockIdx.x * BM;

    int w    = t >> 6;
    int lane = t & 63;
    int l16  = lane & 15;
    int lg   = lane >> 4;
    int g8   = lg * 8;
    int ncol = w * 16;

    // ---- prefetch edge metadata FIRST (L2 latency overlaps B preload).
    int e0 = t >> 3;
    int q  = t & 7;
    int g  = base + e0;
    int j0 = eidx[g];
    int gi = g / 30;                  // exact
    int b_ = gi >> 11;

    // ---- B preload: 13 x 8B independent loads; latency hides under phase 1.
    const unsigned char* wtb = Wt + (size_t)(ncol + l16) * NEIN + g8;
    long bfr[13];
#pragma unroll
    for (int kt = 0; kt < 13; kt++)
        bfr[kt] = *(const long*)(wtb + kt * 32);

    // ---- phase 1: features, p-split, fp8-packed, 2-head recurrence RBF.
    {
        int gj = (b_ << 11) + j0;

        const float4* A4 = atoms5 + (size_t)gi * 5;
        const float4* B4 = atoms5 + (size_t)gj * 5;
        float4* ac = acache + e0 * 10;
        ac[q] = (q < 5) ? A4[q] : B4[q - 5];
        if (q < 2) ac[8 + q] = B4[3 + q];
        __builtin_amdgcn_wave_barrier();

        int off = ridx[gi] - ridx[gj];
        int ec  = (chl[gi] == chl[gj]) ? 1 : 0;
        int dp  = min(max(off + 32, 0), 64);
        dp = ec ? dp : 65;
        {
            float p0 = posW[dp * 16 + 2*q]     + posb[2*q];
            float p1 = posW[dp * 16 + 2*q + 1] + posb[2*q + 1];
            int r = __builtin_amdgcn_cvt_pk_fp8_f32(p0, p1, 0, false);
            *(unsigned short*)&fA[e0][q * 2] = (unsigned short)(r & 0xffff);
        }

        // exp(-(0.8(D-mu_s))^2) = 2^(-(aD - c_s)^2); recurrence over s, 2 heads.
        const float A_ = 0.96089792711f;          // 0.8*sqrt(log2 e)
        const float C0 = 1.92179585422f;          // A_*2
        const float CS = 1.28119723615f;          // A_*(4/3)
        const float E8 = 10.24957789f;            // 8*CS
        const float QQ = __builtin_amdgcn_exp2f(-2.0f * CS * CS);
        auto body = [&](int p) {
            float D;
            if (p == 0) {
                D = dnb[g];
            } else {
                float4 a  = ac[c_PA[p - 1]];
                float4 bb = ac[5 + c_PB[p - 1]];
                float dx = a.x - bb.x, dy = a.y - bb.y, dz = a.z - bb.z;
                D = __builtin_amdgcn_sqrtf(dx*dx + dy*dy + dz*dz + 1e-6f);
            }
            float u0 = D * A_ - C0;
            float f  = __builtin_amdgcn_exp2f(-(u0 * u0));
            float rr = __builtin_amdgcn_exp2f(CS * (2.0f * u0 - CS));
            int wds[4];
#pragma unroll
            for (int gq = 0; gq < 4; gq++) {
                if (gq == 2) {                       // re-seed head at s=8
                    float u8 = u0 - E8;
                    f = __builtin_amdgcn_exp2f(-(u8 * u8));
                }
                float v[4];
#pragma unroll
                for (int u = 0; u < 4; u++) {
                    v[u] = f;
                    f  *= rr;
                    rr *= QQ;
                }
                int r = __builtin_amdgcn_cvt_pk_fp8_f32(v[0], v[1], 0, false);
                r = __builtin_amdgcn_cvt_pk_fp8_f32(v[2], v[3], r, true);
                wds[gq] = r;
            }
            long lo = ((long)(unsigned)wds[1] << 32) | (unsigned)wds[0];
            long hi = ((long)(unsigned)wds[3] << 32) | (unsigned)wds[2];
            *(long*)&fA[e0][16 + p * 16]     = lo;
            *(long*)&fA[e0][16 + p * 16 + 8] = hi;
        };

#pragma unroll
        for (int pp = 0; pp < 3; pp++) body(q + pp * 8);
        if (q == 0) body(24);
    }

    __syncthreads();                               // B1

    // ---- phase 2: GEMM. 52 MFMA + 52 conflict-free ds_read_b64 per wave.
    f32x4 acc[4];
#pragma unroll
    for (int mt = 0; mt < 4; mt++) acc[mt] = (f32x4){0.f, 0.f, 0.f, 0.f};

#pragma unroll
    for (int kt = 0; kt < 13; kt++) {
#pragma unroll
        for (int mt = 0; mt < 4; mt++) {
            long a = *(const long*)(&fA[mt * 16 + l16][kt * 32 + g8]);
            acc[mt] = __builtin_amdgcn_mfma_f32_16x16x32_fp8_fp8(a, bfr[kt], acc[mt], 0, 0, 0);
        }
    }

    __syncthreads();                               // B2: all fA reads done -> staging safe

    // ---- phase 3: stage RAW acc values (no math).
#pragma unroll
    for (int mt = 0; mt < 4; mt++)
#pragma unroll
        for (int r = 0; r < 4; r++) {
            int row = mt * 16 + lg * 4 + r;
            staging[row * SROW + ncol + l16] = acc[mt][r];
        }
    __syncthreads();                               // B3

    // ---- stats: 8 threads per row; 4x b128 reads + 3-step DPP tree over s.
    {
        int row = t >> 3, s = t & 7;
        float ts = 0.f, tq = 0.f;
#pragma unroll
        for (int u = 0; u < 4; u++) {
            f32x4 v = *(f32x4*)&staging[row * SROW + s * 16 + u * 4];
            ts += v.x + v.y + v.z + v.w;
            tq = fmaf(v.x, v.x, tq); tq = fmaf(v.y, v.y, tq);
            tq = fmaf(v.z, v.z, tq); tq = fmaf(v.w, v.w, tq);
        }
        ts = dpp_add<0xB1>(ts); ts = dpp_add<0x4E>(ts); ts = dpp_add<0x141>(ts);
        tq = dpp_add<0xB1>(tq); tq = dpp_add<0x4E>(tq); tq = dpp_add<0x141>(tq);
        if (s == 0) {
            float mu  = ts * (1.0f / 128.0f);
            float var = tq * (1.0f / 128.0f) - mu * mu;
            float rs  = 1.0f / sqrtf(var + 1e-5f);
            red2[row * 2 + 0] = rs;
            red2[row * 2 + 1] = mu * rs;
        }
    }
    __syncthreads();                               // B4

    // ---- phase 4: store loop with inline normalize (2 FMA/elem), full-line stream.
    int c4s = t & 31;
    f32x4 sc4 = *(const f32x4*)&lns[c4s * 4];
    f32x4 of4 = *(const f32x4*)&lno[c4s * 4];
    f32x4* Eout4 = (f32x4*)Eout;
#pragma unroll
    for (int u = 0; u < 4; u++) {
        int idx  = u * 512 + t;                    // 0..2047
        int lrow = idx >> 5;
        f32x4 v = *(f32x4*)&staging[lrow * SROW + c4s * 4];
        float rs   = red2[lrow * 2 + 0];
        float murs = red2[lrow * 2 + 1];
        f32x4 o;
        o.x = fmaf(sc4.x, fmaf(v.x, rs, -murs), of4.x);
        o.y = fmaf(sc4.y, fmaf(v.y, rs, -murs), of4.y);
        o.z = fmaf(sc4.z, fmaf(v.z, rs, -murs), of4.z);
        o.w = fmaf(sc4.w, fmaf(v.w, rs, -murs), of4.w);
        Eout4[(size_t)(base + lrow) * 32 + c4s] = o;
    }
    // no trailing barrier: stores drain as waves retire
}

extern "C" void kernel_launch(void* const* d_in, const int* in_sizes, int n_in,
                              void* d_out, int out_size, void* d_ws, size_t ws_size,
                              hipStream_t stream)
{
    const float* X    = (const float*)d_in[0];
    const float* mask = (const float*)d_in[1];
    const int*   ridx = (const int*)d_in[2];
    const int*   chl  = (const int*)d_in[3];
    const float* posW = (const float*)d_in[4];
    const float* posb = (const float*)d_in[5];
    const float* eW   = (const float*)d_in[6];
    const float* lns  = (const float*)d_in[7];
    const float* lno  = (const float*)d_in[8];

    float* Eout   = (float*)d_out;                                  // B*L*K*128
    float* eidx_f = Eout + (size_t)NB * NL * NK * NEF;              // B*L*K (as float)

    char* ws = (char*)d_ws;
    float4*        atoms5 = (float4*)ws;                            // 327680 B
    float*         dnb    = (float*)(ws + 327680);                  // 491520 B
    int*           eidx   = (int*)(ws + 819200);                    // 491520 B
    unsigned char* Wt     = (unsigned char*)(ws + 1310720);         // 53248 B

    k_front<<<572, 512, 0, stream>>>(X, mask, eW, atoms5, Wt, dnb, eidx, eidx_f);
    k_edge<<<(NB * NL * NK) / BM, 512, 0, stream>>>(atoms5, eidx, dnb, ridx, chl,
                                                    posW, posb, Wt, lns, lno, Eout);
}